// Round 1
// baseline (114.562 us; speedup 1.0000x reference)
//
#include <hip/hip_runtime.h>

#define IN_CH 128
#define NHC   64   // HEADS*OUT_CH
#define OUT_C 16

// ws layout: [0, 4*n_nodes) flags ints; at byte 1<<20: mode int
// mode = 1 -> edge_index buffer is int32, col at words [E, 2E)
// mode = 0 -> edge_index buffer is int64, col low words at 2E + 2e

// flags[i] = 0 for all nodes; block 0 additionally probes the edge-index layout.
__global__ void init_kernel(const int* __restrict__ ei, int* __restrict__ flags,
                            int* __restrict__ mode, int n_nodes) {
    int i = blockIdx.x * blockDim.x + threadIdx.x;
    if (i < n_nodes) flags[i] = 0;
    if (blockIdx.x == 0) {
        __shared__ int s_mode;
        if (threadIdx.x == 0) s_mode = 0;
        __syncthreads();
        // Odd int32 words of first 512: int64 layout -> high halves of values
        // < 2^31 -> all zero. int32 layout -> random node ids, ~surely nonzero.
        int v = ei[2 * threadIdx.x + 1];
        if (v != 0) atomicOr(&s_mode, 1);
        __syncthreads();
        if (threadIdx.x == 0) *mode = s_mode;
    }
}

// Scalar fallback (E not divisible by 4): flags[col[e]] = 1
__global__ void flag_kernel(const int* __restrict__ ei, const int* __restrict__ mode,
                            int* __restrict__ flags, int E, int n_nodes) {
    int e = blockIdx.x * blockDim.x + threadIdx.x;
    if (e >= E) return;
    int m = *mode;  // wave-uniform scalar load
    int c = m ? ei[E + e]           // int32 layout
              : ei[2 * E + 2 * e];  // int64 layout: low word of col[e]
    if ((unsigned)c < (unsigned)n_nodes) flags[c] = 1;
}

// Vectorized: 4 edges/thread, 16B loads in both layouts. Requires E % 4 == 0
// (host checks) so the int4 loads are 16B-aligned.
__global__ __launch_bounds__(256) void flag_kernel4(
    const int* __restrict__ ei, const int* __restrict__ mode,
    int* __restrict__ flags, int E, int n_nodes) {
    int e0 = (blockIdx.x * blockDim.x + threadIdx.x) * 4;
    if (e0 >= E) return;
    int m = *mode;  // wave-uniform
    int c0, c1, c2, c3;
    if (m) {
        // int32 layout: col = words [E, 2E)
        int4 v = *(const int4*)(ei + E + e0);
        c0 = v.x; c1 = v.y; c2 = v.z; c3 = v.w;
    } else {
        // int64 layout: col[e] low word at 2E + 2e (little-endian, ids < 2^31)
        int4 a = *(const int4*)(ei + 2 * E + 2 * e0);
        int4 b = *(const int4*)(ei + 2 * E + 2 * e0 + 4);
        c0 = a.x; c1 = a.z; c2 = b.x; c3 = b.z;
    }
    if ((unsigned)c0 < (unsigned)n_nodes) flags[c0] = 1;
    if ((unsigned)c1 < (unsigned)n_nodes) flags[c1] = 1;
    if ((unsigned)c2 < (unsigned)n_nodes) flags[c2] = 1;
    if ((unsigned)c3 < (unsigned)n_nodes) flags[c3] = 1;
}

// out[n,c] = flag[n] * dot(x[n,:], Wm[:,c]),  Wm[k,c] = 0.25*sum_h W[k,h*16+c]
// 256 threads -> 256 nodes/block; lane (g,q): g=tid>>2 node sub-index, q=tid&3
// channel quad. Each thread processes 4 nodes (g, g+64, g+128, g+192) so every
// LDS weight quad read is reused 4x (ds_read_b128 count per node drops 8 -> 2).
__global__ __launch_bounds__(256) void out_kernel(
    const float* __restrict__ x,     // fp32 [N,128]
    const float* __restrict__ W,     // fp32 [128,64]
    const int* __restrict__ flags,
    float* __restrict__ out,         // fp32 [N,16]
    int n_nodes)
{
    __shared__ alignas(16) float wlds[IN_CH * OUT_C];  // 8 KB
    const int tid = threadIdx.x;

    for (int i = tid; i < IN_CH * OUT_C; i += 256) {
        int k = i >> 4, c = i & 15;
        const float* wr = W + k * NHC + c;
        wlds[i] = 0.25f * (wr[0] + wr[16] + wr[32] + wr[48]);
    }
    __syncthreads();

    const int g = tid >> 2;          // node sub-index 0..63
    const int q = tid & 3;           // channel quad
    const int base = blockIdx.x * 256 + g;
    const int last = n_nodes - 1;

    const int n0 = min(base,       last);
    const int n1 = min(base + 64,  last);
    const int n2 = min(base + 128, last);
    const int n3 = min(base + 192, last);

    const float4* x4 = (const float4*)x;
    const float4* w4 = (const float4*)wlds;
    const size_t b0 = (size_t)n0 * (IN_CH / 4);
    const size_t b1 = (size_t)n1 * (IN_CH / 4);
    const size_t b2 = (size_t)n2 * (IN_CH / 4);
    const size_t b3 = (size_t)n3 * (IN_CH / 4);

    float4 a0 = make_float4(0.f, 0.f, 0.f, 0.f);
    float4 a1 = make_float4(0.f, 0.f, 0.f, 0.f);
    float4 a2 = make_float4(0.f, 0.f, 0.f, 0.f);
    float4 a3 = make_float4(0.f, 0.f, 0.f, 0.f);

    #pragma unroll 2
    for (int kk = 0; kk < IN_CH / 4; ++kk) {
        // 4 lanes per node share each address -> wave fetches 16 distinct 16B
        // row chunks per instr (full 64B line coverage), same pattern as before.
        float4 v0 = x4[b0 + kk];
        float4 v1 = x4[b1 + kk];
        float4 v2 = x4[b2 + kk];
        float4 v3 = x4[b3 + kk];
        float f0[4] = {v0.x, v0.y, v0.z, v0.w};
        float f1[4] = {v1.x, v1.y, v1.z, v1.w};
        float f2[4] = {v2.x, v2.y, v2.z, v2.w};
        float f3[4] = {v3.x, v3.y, v3.z, v3.w};
        #pragma unroll
        for (int i = 0; i < 4; ++i) {
            // 4 distinct LDS addresses/wave, 16-way same-address broadcast,
            // now amortized over 4 nodes per thread.
            float4 w = w4[(kk * 4 + i) * 4 + q];
            a0.x += f0[i] * w.x; a0.y += f0[i] * w.y; a0.z += f0[i] * w.z; a0.w += f0[i] * w.w;
            a1.x += f1[i] * w.x; a1.y += f1[i] * w.y; a1.z += f1[i] * w.z; a1.w += f1[i] * w.w;
            a2.x += f2[i] * w.x; a2.y += f2[i] * w.y; a2.z += f2[i] * w.z; a2.w += f2[i] * w.w;
            a3.x += f3[i] * w.x; a3.y += f3[i] * w.y; a3.z += f3[i] * w.z; a3.w += f3[i] * w.w;
        }
    }

    float4* o4 = (float4*)out;
    // float4 index node*4+q: consecutive across the wave -> 1KB coalesced store
    if (base < n_nodes) {
        float s = flags[n0] ? 1.0f : 0.0f;
        o4[(size_t)n0 * 4 + q] = make_float4(a0.x * s, a0.y * s, a0.z * s, a0.w * s);
    }
    if (base + 64 < n_nodes) {
        float s = flags[n1] ? 1.0f : 0.0f;
        o4[(size_t)n1 * 4 + q] = make_float4(a1.x * s, a1.y * s, a1.z * s, a1.w * s);
    }
    if (base + 128 < n_nodes) {
        float s = flags[n2] ? 1.0f : 0.0f;
        o4[(size_t)n2 * 4 + q] = make_float4(a2.x * s, a2.y * s, a2.z * s, a2.w * s);
    }
    if (base + 192 < n_nodes) {
        float s = flags[n3] ? 1.0f : 0.0f;
        o4[(size_t)n3 * 4 + q] = make_float4(a3.x * s, a3.y * s, a3.z * s, a3.w * s);
    }
}

extern "C" void kernel_launch(void* const* d_in, const int* in_sizes, int n_in,
                              void* d_out, int out_size, void* d_ws, size_t ws_size,
                              hipStream_t stream) {
    const float* x        = (const float*)d_in[0];  // fp32 [N,128]
    const int*   ei       = (const int*)d_in[1];    // int32 or int64 [2,E] (probed)
    const float* W        = (const float*)d_in[2];  // fp32 [128,64]
    // d_in[3] (att) is mathematically irrelevant: segment-softmax weights sum
    // to 1 and multiply the segment-constant vector x_proj[col].

    const int E       = in_sizes[1] / 2;
    const int n_nodes = in_sizes[0] / IN_CH;

    int* flags = (int*)d_ws;
    int* mode  = (int*)((char*)d_ws + (1 << 20));

    init_kernel<<<dim3((n_nodes + 255) / 256), dim3(256), 0, stream>>>(ei, flags, mode, n_nodes);
    if ((E & 3) == 0) {
        flag_kernel4<<<dim3((E / 4 + 255) / 256), dim3(256), 0, stream>>>(ei, mode, flags, E, n_nodes);
    } else {
        flag_kernel<<<dim3((E + 255) / 256), dim3(256), 0, stream>>>(ei, mode, flags, E, n_nodes);
    }
    out_kernel<<<dim3((n_nodes + 255) / 256), dim3(256), 0, stream>>>(
        x, W, flags, (float*)d_out, n_nodes);
}